// Round 2
// 21784.351 us; speedup vs baseline: 1.0136x; 1.0136x over previous
//
#include <hip/hip_runtime.h>
#include <cstdint>

// RoleConditionedLSTMDecoder on MI355X (gfx950) — R10.
// = R9 design (256x256 8-phase counted-vmcnt GEMM for S1/S2) with launch
//   mechanics fixed: STATIC 128 KiB __shared__ (no dynamic LDS, no
//   hipFuncSetAttribute — R9's dynamic-LDS launch was the suspected
//   container-killer), and sched_barrier(0) sealing each MFMA cluster so
//   register-only MFMAs cannot sink past the trailing s_barrier (rule #18).
// Schedule: 512 thr / 8 waves (2Mx4N), BK=64 split in 2 k-halves, double
//   buffered; per phase {ds_read subtile | stage 1 quarter | barrier |
//   16 MFMA (setprio) | barrier}; vmcnt(4) only at phases 4/8.
// Gate-permuted weight rows: cg = bn*64 + (wn>>1)*32 + (wn&1)*16 + c16,
//   gate = nf (prep kernels unchanged from R8).

#define DEVI __device__ __forceinline__

typedef __bf16 bf16x8 __attribute__((ext_vector_type(8)));
typedef float  f32x4  __attribute__((ext_vector_type(4)));
typedef float  f32x2  __attribute__((ext_vector_type(2)));
typedef unsigned short u16x4 __attribute__((ext_vector_type(4)));

static constexpr int NROWS = 22528;   // B*P
static constexpr int T_STEPS = 100;
static constexpr int NBM = 176;       // 22528/128 row-tiles (k_static only)

DEVI unsigned short f2bf(float f) {
  unsigned u = __float_as_uint(f);
  u = u + 0x7FFFu + ((u >> 16) & 1u);   // RNE
  return (unsigned short)(u >> 16);
}
DEVI float bf2f(unsigned short h) { return __uint_as_float(((unsigned)h) << 16); }

DEVI float fast_sigmoid(float x) {
  float e = __builtin_amdgcn_exp2f(-1.442695041f * x);
  return __builtin_amdgcn_rcpf(1.0f + e);
}
DEVI float fast_tanh(float x) {
  float e = __builtin_amdgcn_exp2f(2.885390082f * x);   // e^(2x)
  return 1.0f - 2.0f * __builtin_amdgcn_rcpf(e + 1.0f);
}

DEVI void async_copy16(const void* g, void* l) {
  __builtin_amdgcn_global_load_lds(
      (const __attribute__((address_space(1))) void*)g,
      (__attribute__((address_space(3))) void*)l, 16, 0, 0);
}

// ---------------- 128x128 GEMM core (k_static only) — proven ----------------
template <int KITERS, int KSWITCH>
DEVI void gemm_core(const unsigned short* __restrict__ A1, int lda1,
                    const unsigned short* __restrict__ A2, int lda2,
                    const unsigned short* __restrict__ B1, int ldb1,
                    const unsigned short* __restrict__ B2, int ldb2,
                    unsigned short* lds, f32x4 acc[4][4], int tid) {
  const int lane = tid & 63, wid = tid >> 6;
  const int wm = wid & 1, wn = wid >> 1;
  const int c16 = lane & 15, q = lane >> 4;
#pragma unroll
  for (int i = 0; i < 4; ++i)
#pragma unroll
    for (int j = 0; j < 4; ++j) acc[i][j] = f32x4{0.f, 0.f, 0.f, 0.f};
#pragma unroll
  for (int kt = 0; kt < KITERS; ++kt) {
    const bool sec = (kt >= KSWITCH);
    const unsigned short* Ab = sec ? A2 : A1;
    const unsigned short* Bb = sec ? B2 : B1;
    const int lda = sec ? lda2 : lda1;
    const int ldb = sec ? ldb2 : ldb1;
    const int kk = (sec ? (kt - KSWITCH) : kt) * 64;
    __syncthreads();
#pragma unroll
    for (int rd = 0; rd < 4; ++rd) {
      int p = rd * 256 + tid;
      int row = p >> 3, u = p & 7, ch = u ^ (row & 7);
      async_copy16(Ab + row * lda + kk + ch * 8, lds + p * 8);
      async_copy16(Bb + row * ldb + kk + ch * 8, lds + 8192 + p * 8);
    }
    __syncthreads();
#pragma unroll
    for (int s = 0; s < 2; ++s) {
      bf16x8 a[4], b[4];
#pragma unroll
      for (int mf = 0; mf < 4; ++mf) {
        int row = wm * 64 + mf * 16 + c16;
        int slot = row * 8 + ((s * 4 + q) ^ (row & 7));
        a[mf] = *(const bf16x8*)(lds + slot * 8);
      }
#pragma unroll
      for (int nf = 0; nf < 4; ++nf) {
        int row = wn * 64 + nf * 16 + c16;
        int slot = row * 8 + ((s * 4 + q) ^ (row & 7));
        b[nf] = *(const bf16x8*)(lds + 8192 + slot * 8);
      }
#pragma unroll
      for (int mf = 0; mf < 4; ++mf)
#pragma unroll
        for (int nf = 0; nf < 4; ++nf)
          acc[mf][nf] = __builtin_amdgcn_mfma_f32_16x16x32_bf16(a[mf], b[nf], acc[mf][nf], 0, 0, 0);
    }
  }
}

// ---------------- prep ----------------
DEVI int orig_row(int j) {  // permuted gate-col -> original row of [4H x K] weight
  int tile = j >> 7, rem = j & 127;
  int half = rem >> 6, g = (rem >> 4) & 3, cc = rem & 15;
  return g * 512 + (tile * 32 + half * 16 + cc);
}

__global__ void k_prep_w(const float* __restrict__ Whh0, const float* __restrict__ Wih1,
                         const float* __restrict__ Whh1, const float* __restrict__ Wih0,
                         const float* __restrict__ Wfc1, const float* __restrict__ b0,
                         const float* __restrict__ b1,
                         unsigned short* __restrict__ W0p, unsigned short* __restrict__ Wc1p,
                         unsigned short* __restrict__ Wsp, unsigned short* __restrict__ Wfc1b,
                         float* __restrict__ Wposx, float* __restrict__ Wposy,
                         float* __restrict__ b0p4, float* __restrict__ b1p4) {
  int j = blockIdx.x;       // 0..2047
  int k = threadIdx.x;      // 0..511
  int o = orig_row(j);
  W0p[j * 512 + k]         = f2bf(Whh0[o * 512 + k]);
  Wc1p[j * 1024 + k]       = f2bf(Wih1[o * 512 + k]);
  Wc1p[j * 1024 + 512 + k] = f2bf(Whh1[o * 512 + k]);
  if (k < 384) Wsp[j * 384 + k] = (k < 322) ? f2bf(Wih0[o * 324 + 2 + k]) : (unsigned short)0;
  if (k == 0) {
    int g = (j >> 4) & 3;
    int cg = (j >> 7) * 32 + ((j >> 6) & 1) * 16 + (j & 15);
    Wposx[cg * 4 + g] = Wih0[o * 324 + 0];
    Wposy[cg * 4 + g] = Wih0[o * 324 + 1];
    b0p4[cg * 4 + g] = b0[o];
    b1p4[cg * 4 + g] = b1[o];
  }
  if (j < 256) Wfc1b[j * 512 + k] = f2bf(Wfc1[j * 512 + k]);
}

__global__ void k_init_xs(const float* __restrict__ ball, const float* __restrict__ ctx,
                          const int* __restrict__ roles, const float* __restrict__ role_table,
                          unsigned short* __restrict__ Xs) {
  int n = blockIdx.x, col = threadIdx.x;  // 22528 x 384
  int b = n / 22;
  float v;
  if (col < 2)        v = ball[b * 2 + col];
  else if (col < 258) v = ctx[(size_t)n * 256 + col - 2];
  else if (col < 322) v = role_table[roles[n] * 64 + col - 258];
  else                v = 0.f;
  Xs[(size_t)n * 384 + col] = f2bf(v);
}

__global__ void k_init_state(const float* __restrict__ pos0, const float* __restrict__ Winit,
                             const float* __restrict__ binit, unsigned short* __restrict__ Hcat,
                             float* __restrict__ c0, float* __restrict__ c1,
                             float* __restrict__ posb) {
  int idx = blockIdx.x * 256 + threadIdx.x;     // N*512
  if (idx >= NROWS * 512) return;
  int n = idx >> 9, c = idx & 511;
  float px = pos0[n * 2 + 0], py = pos0[n * 2 + 1];
  float h0 = binit[c] + Winit[c * 2 + 0] * px + Winit[c * 2 + 1] * py;
  Hcat[(size_t)n * 1024 + c] = f2bf(h0);
  Hcat[(size_t)n * 1024 + 512 + c] = 0;   // h1 = 0
  c0[idx] = 0.f;
  c1[idx] = 0.f;
  if (c < 2) posb[n * 2 + c] = pos0[n * 2 + c];
}

// static_proj packed: SP2[row*512+cg] = ushort4{i,f,g,o} + b0 — SP path only
__global__ __launch_bounds__(256) void k_static(const unsigned short* __restrict__ Xs,
                                                const unsigned short* __restrict__ Wsp,
                                                const float* __restrict__ b0p4,
                                                unsigned short* __restrict__ SP2) {
  __shared__ __align__(16) unsigned short lds[16384];
  int tid = threadIdx.x, bn = blockIdx.x, bm = blockIdx.y;
  f32x4 acc[4][4];
  const unsigned short* Ab = Xs + (size_t)bm * 128 * 384;
  const unsigned short* Bb = Wsp + (size_t)bn * 128 * 384;
  gemm_core<6, 6>(Ab, 384, Ab, 384, Bb, 384, Bb, 384, lds, acc, tid);
  int lane = tid & 63, wid = tid >> 6, wm = wid & 1, wn = wid >> 1;
  int c16 = lane & 15, q = lane >> 4;
  int cg = bn * 32 + wn * 16 + c16;
  f32x4 bb = *(const f32x4*)&b0p4[cg * 4];
#pragma unroll
  for (int mf = 0; mf < 4; ++mf) {
    int row0 = bm * 128 + wm * 64 + mf * 16 + q * 4;
#pragma unroll
    for (int r = 0; r < 4; ++r) {
      u16x4 v;
      v.x = f2bf(acc[mf][0][r] + bb.x);
      v.y = f2bf(acc[mf][1][r] + bb.y);
      v.z = f2bf(acc[mf][2][r] + bb.z);
      v.w = f2bf(acc[mf][3][r] + bb.w);
      ((u16x4*)SP2)[(size_t)(row0 + r) * 512 + cg] = v;
    }
  }
}

// ---------------- 256x256 8-phase GEMM core (S1/S2) ----------------
// LDS: [2 buf][A kh0 | A kh1 | B kh0 | B kh1] quarters of 8 KB-words (16 KB)
// = 128 KiB static. Quarter = 2 gload_lds dwordx4/thread. Swizzle: chunk u
// holds source chunk u ^ ((row>>1)&3) — 2-way aliasing max (free), same
// involution on stage-source and ds_read (rule 21).
// vmcnt ledger (2 loads/quarter-stage/thread): prologue 12 loads, vmcnt(4)
// -> T0 landed, T1kh0 in flight. Steady state: vmcnt(4) at ph4/ph8 leaves
// exactly the 2 newest quarters outstanding; every restage target's readers
// completed before the preceding barrier (compiler lgkmcnt before MFMA +
// sched_barrier(0) pinning the cluster above the trailing s_barrier).
// Tail: source-clamped fake stages into dead regions keep the ledger exact.

struct GemmSrc {
  const unsigned short *A1, *A2, *B1, *B2;
  int ldA1, ldA2, ldB1, ldB2;
};

template <int KT, int KSW>
DEVI void stage_q(const GemmSrc& g, int t, int s, int isB, unsigned short* dst, int tid) {
  int tt = (t >= KT) ? (t - 2) : t;        // tail: clamp source, keep counts
  const bool sec = (tt >= KSW);
  const unsigned short* base;
  int ld;
  if (isB) { base = sec ? g.B2 : g.B1; ld = sec ? g.ldB2 : g.ldB1; }
  else     { base = sec ? g.A2 : g.A1; ld = sec ? g.ldA2 : g.ldA1; }
  base += (sec ? (tt - KSW) : tt) * 64 + s * 32;
#pragma unroll
  for (int rd = 0; rd < 2; ++rd) {
    int p = rd * 512 + tid;
    int row = p >> 2, u = p & 3, ch = u ^ ((row >> 1) & 3);
    async_copy16(base + row * ld + ch * 8, dst + p * 8);
  }
}

#define GBAR   asm volatile("s_barrier" ::: "memory")
#define VMCNT4 asm volatile("s_waitcnt vmcnt(4)" ::: "memory")

template <int KT, int KSW>
DEVI void gemm8(const GemmSrc& g, unsigned short* lds, f32x4 acc[8][4], int tid) {
  const int lane = tid & 63, wid = tid >> 6;
  const int wm = wid >> 2, wn = wid & 3;
  const int c16 = lane & 15, q = lane >> 4;
#pragma unroll
  for (int i = 0; i < 8; ++i)
#pragma unroll
    for (int j = 0; j < 4; ++j) acc[i][j] = f32x4{0.f, 0.f, 0.f, 0.f};
  unsigned short* A00 = lds;              // buf0 A khalf0
  unsigned short* A01 = lds + 8192;       // buf0 A khalf1
  unsigned short* B00 = lds + 16384;
  unsigned short* B01 = lds + 24576;
  unsigned short* A10 = lds + 32768;      // buf1
  unsigned short* A11 = lds + 40960;
  unsigned short* B10 = lds + 49152;
  unsigned short* B11 = lds + 57344;
  const int rowA0 = wm * 128 + c16;
  const int rowB0 = wn * 64 + c16;
  // prologue: T0 all 4 quarters + T1 khalf0 (12 loads); wait first 8 (=T0)
  stage_q<KT, KSW>(g, 0, 0, 0, A00, tid);
  stage_q<KT, KSW>(g, 0, 0, 1, B00, tid);
  stage_q<KT, KSW>(g, 0, 1, 0, A01, tid);
  stage_q<KT, KSW>(g, 0, 1, 1, B01, tid);
  stage_q<KT, KSW>(g, 1, 0, 0, A10, tid);
  stage_q<KT, KSW>(g, 1, 0, 1, B10, tid);
  VMCNT4;
  GBAR;
  bf16x8 a[4], b[4];

#define LOADA(BASE, MG)                                                        \
  _Pragma("unroll")                                                            \
  for (int f = 0; f < 4; ++f) {                                                \
    int row = rowA0 + ((MG) * 4 + f) * 16;                                     \
    a[f] = *(const bf16x8*)((BASE) + (row * 4 + (q ^ ((row >> 1) & 3))) * 8);  \
  }
#define LOADB(BASE)                                                            \
  _Pragma("unroll")                                                            \
  for (int f = 0; f < 4; ++f) {                                                \
    int row = rowB0 + f * 16;                                                  \
    b[f] = *(const bf16x8*)((BASE) + (row * 4 + (q ^ ((row >> 1) & 3))) * 8);  \
  }
#define MFG(MG)                                                                \
  __builtin_amdgcn_s_setprio(1);                                               \
  _Pragma("unroll")                                                            \
  for (int f = 0; f < 4; ++f)                                                  \
    _Pragma("unroll")                                                          \
    for (int nf = 0; nf < 4; ++nf)                                             \
      acc[(MG) * 4 + f][nf] = __builtin_amdgcn_mfma_f32_16x16x32_bf16(         \
          a[f], b[nf], acc[(MG) * 4 + f][nf], 0, 0, 0);                        \
  __builtin_amdgcn_s_setprio(0);                                               \
  __builtin_amdgcn_sched_barrier(0);   /* pin cluster above trailing GBAR */

#pragma unroll 1
  for (int it = 0; it < KT / 2; ++it) {
    const int t0 = 2 * it;
    // ph1: tile t0 kh0, m-group 0 | stage A(t0+1) kh1
    LOADA(A00, 0); LOADB(B00);
    stage_q<KT, KSW>(g, t0 + 1, 1, 0, A11, tid);
    GBAR; MFG(0); GBAR;
    // ph2: m-group 1 (reuse b) | stage B(t0+1) kh1
    LOADA(A00, 1);
    stage_q<KT, KSW>(g, t0 + 1, 1, 1, B11, tid);
    GBAR; MFG(1); GBAR;
    // ph3: tile t0 kh1, mg0 | stage A(t0+2) kh0 (A00 free since ph2)
    LOADA(A01, 0); LOADB(B01);
    stage_q<KT, KSW>(g, t0 + 2, 0, 0, A00, tid);
    GBAR; MFG(0); GBAR;
    // ph4: mg1 | stage B(t0+2) kh0 (B00 free since ph1) | vmcnt(4)
    LOADA(A01, 1);
    stage_q<KT, KSW>(g, t0 + 2, 0, 1, B00, tid);
    GBAR; MFG(1); VMCNT4; GBAR;
    // ph5: tile t0+1 kh0, mg0 | stage A(t0+2) kh1
    LOADA(A10, 0); LOADB(B10);
    stage_q<KT, KSW>(g, t0 + 2, 1, 0, A01, tid);
    GBAR; MFG(0); GBAR;
    // ph6: mg1 | stage B(t0+2) kh1
    LOADA(A10, 1);
    stage_q<KT, KSW>(g, t0 + 2, 1, 1, B01, tid);
    GBAR; MFG(1); GBAR;
    // ph7: tile t0+1 kh1, mg0 | stage A(t0+3) kh0
    LOADA(A11, 0); LOADB(B11);
    stage_q<KT, KSW>(g, t0 + 3, 0, 0, A10, tid);
    GBAR; MFG(0); GBAR;
    // ph8: mg1 | stage B(t0+3) kh0 | vmcnt(4)
    LOADA(A11, 1);
    stage_q<KT, KSW>(g, t0 + 3, 0, 1, B10, tid);
    GBAR; MFG(1); VMCNT4; GBAR;
  }
  asm volatile("s_waitcnt vmcnt(0)" ::: "memory");   // drain tail fakes
#undef LOADA
#undef LOADB
#undef MFG
}

// XCD swizzle for 704-block grid: bm ≡ xcd (mod 8) -> A-panel reuse per XCD.
DEVI void swz704(int l, int& bn, int& bm) {
  int xcd = l & 7, ii = l >> 3;   // ii in 0..87
  bn = ii & 7;
  bm = (ii >> 3) * 8 + xcd;       // 11 bm per xcd
}

// ---------------- per-step ----------------
// S1: gates0 = h0_prev @ W0p^T (+ static) + pos@Wpos^T ; cell0 -> h0 into nxt[:,0:512]
template <bool USE_SP>
__global__ __launch_bounds__(512, 2) void k_s1_8(const unsigned short* __restrict__ cur,
                                                 const unsigned short* __restrict__ Xs,
                                                 const unsigned short* __restrict__ W0p,
                                                 const unsigned short* __restrict__ Wsp,
                                                 const unsigned short* __restrict__ SP2,
                                                 const float* __restrict__ b0p4,
                                                 const float* __restrict__ Wposx,
                                                 const float* __restrict__ Wposy,
                                                 const float* __restrict__ posb,
                                                 float* __restrict__ c0,
                                                 unsigned short* __restrict__ nxt) {
  __shared__ __align__(16) unsigned short lds[65536];   // 128 KiB static
  const int tid = threadIdx.x;
  int bn, bm;
  swz704(blockIdx.x, bn, bm);
  f32x4 acc[8][4];
  GemmSrc g;
  g.A1 = cur + (size_t)bm * 256 * 1024; g.ldA1 = 1024;
  g.B1 = W0p + (size_t)bn * 256 * 512;  g.ldB1 = 512;
  if constexpr (USE_SP) {
    g.A2 = g.A1; g.ldA2 = 1024; g.B2 = g.B1; g.ldB2 = 512;
    gemm8<8, 8>(g, lds, acc, tid);
  } else {
    g.A2 = Xs + (size_t)bm * 256 * 384;  g.ldA2 = 384;
    g.B2 = Wsp + (size_t)bn * 256 * 384; g.ldB2 = 384;
    gemm8<14, 8>(g, lds, acc, tid);
  }
  const int lane = tid & 63, wid = tid >> 6;
  const int wm = wid >> 2, wn = wid & 3;
  const int c16 = lane & 15, q = lane >> 4;
  const int cg = bn * 64 + (wn >> 1) * 32 + (wn & 1) * 16 + c16;
  f32x4 wpx = *(const f32x4*)&Wposx[cg * 4];
  f32x4 wpy = *(const f32x4*)&Wposy[cg * 4];
  f32x4 sb = f32x4{0.f, 0.f, 0.f, 0.f};
  if constexpr (!USE_SP) sb = *(const f32x4*)&b0p4[cg * 4];
#pragma unroll
  for (int mf = 0; mf < 8; ++mf) {
    int row0 = bm * 256 + wm * 128 + mf * 16 + q * 4;
    f32x4 cold = *(const f32x4*)&c0[(size_t)cg * NROWS + row0];
    f32x4 cnew;
#pragma unroll
    for (int r = 0; r < 4; ++r) {
      size_t row = row0 + r;
      f32x2 pv = *(const f32x2*)&posb[row * 2];
      float s0 = sb.x, s1 = sb.y, s2 = sb.z, s3 = sb.w;
      if constexpr (USE_SP) {
        u16x4 sp = ((const u16x4*)SP2)[row * 512 + cg];
        s0 = bf2f(sp.x); s1 = bf2f(sp.y); s2 = bf2f(sp.z); s3 = bf2f(sp.w);
      }
      float gi = acc[mf][0][r] + s0 + pv.x * wpx.x + pv.y * wpy.x;
      float gf = acc[mf][1][r] + s1 + pv.x * wpx.y + pv.y * wpy.y;
      float gg = acc[mf][2][r] + s2 + pv.x * wpx.z + pv.y * wpy.z;
      float go = acc[mf][3][r] + s3 + pv.x * wpx.w + pv.y * wpy.w;
      float cn = fast_sigmoid(gf) * cold[r] + fast_sigmoid(gi) * fast_tanh(gg);
      cnew[r] = cn;
      nxt[row * 1024 + cg] = f2bf(fast_sigmoid(go) * fast_tanh(cn));
    }
    *(f32x4*)&c0[(size_t)cg * NROWS + row0] = cnew;
  }
}

// S2: gates1 = [h0_t | h1_prev] @ Wc1p^T + b1 ; cell1 -> h1 into nxt[:,512:]
__global__ __launch_bounds__(512, 2) void k_s2_8(const unsigned short* __restrict__ nxt_in,
                                                 const unsigned short* __restrict__ cur,
                                                 const unsigned short* __restrict__ Wc1p,
                                                 const float* __restrict__ b1p4,
                                                 float* __restrict__ c1,
                                                 unsigned short* __restrict__ nxt_out) {
  __shared__ __align__(16) unsigned short lds[65536];   // 128 KiB static
  const int tid = threadIdx.x;
  int bn, bm;
  swz704(blockIdx.x, bn, bm);
  f32x4 acc[8][4];
  GemmSrc g;
  g.A1 = nxt_in + (size_t)bm * 256 * 1024;      g.ldA1 = 1024;   // h0_t
  g.A2 = cur + (size_t)bm * 256 * 1024 + 512;   g.ldA2 = 1024;   // h1_{t-1}
  g.B1 = Wc1p + (size_t)bn * 256 * 1024;        g.ldB1 = 1024;
  g.B2 = g.B1 + 512;                            g.ldB2 = 1024;
  gemm8<16, 8>(g, lds, acc, tid);
  const int lane = tid & 63, wid = tid >> 6;
  const int wm = wid >> 2, wn = wid & 3;
  const int c16 = lane & 15, q = lane >> 4;
  const int cg = bn * 64 + (wn >> 1) * 32 + (wn & 1) * 16 + c16;
  f32x4 bv = *(const f32x4*)&b1p4[cg * 4];
#pragma unroll
  for (int mf = 0; mf < 8; ++mf) {
    int row0 = bm * 256 + wm * 128 + mf * 16 + q * 4;
    f32x4 cold = *(const f32x4*)&c1[(size_t)cg * NROWS + row0];
    f32x4 cnew;
#pragma unroll
    for (int r = 0; r < 4; ++r) {
      size_t row = row0 + r;
      float gi = acc[mf][0][r] + bv.x;
      float gf = acc[mf][1][r] + bv.y;
      float gg = acc[mf][2][r] + bv.z;
      float go = acc[mf][3][r] + bv.w;
      float cn = fast_sigmoid(gf) * cold[r] + fast_sigmoid(gi) * fast_tanh(gg);
      cnew[r] = cn;
      nxt_out[row * 1024 + 512 + cg] = f2bf(fast_sigmoid(go) * fast_tanh(cn));
    }
    *(f32x4*)&c1[(size_t)cg * NROWS + row0] = cnew;
  }
}

// S3: pos = relu(h1 @ Wfc1^T + bfc1) @ Wfc2^T + bfc2 ; write preds[:,t], posb.
// 704 blocks x 32 rows x 256 cols; 4 waves, wave w = 32 rows x 64 cols.
__global__ __launch_bounds__(256) void k_s3(const unsigned short* __restrict__ H,
                                            const unsigned short* __restrict__ Wfc1b,
                                            const float* __restrict__ bfc1,
                                            const float* __restrict__ Wfc2,
                                            const float* __restrict__ bfc2,
                                            float* __restrict__ out, float* __restrict__ posb,
                                            int t) {
  __shared__ __align__(16) unsigned short ldsA[32 * 64];    // 4 KB
  __shared__ __align__(16) unsigned short ldsB[256 * 64];   // 32 KB
  __shared__ float wfc2s[512];
  __shared__ float red[32 * 8];                             // [row][wave*2+d]
  int tid = threadIdx.x;
  int l = blockIdx.x, xcd = l & 7, i = l >> 3;              // i in 0..87
  int b32 = 4 * (xcd + 8 * (i >> 2)) + (i & 3);             // 0..703
  wfc2s[tid] = Wfc2[tid];
  wfc2s[tid + 256] = Wfc2[tid + 256];
  int lane = tid & 63, wid = tid >> 6;                      // wid = wave col-group
  int c16 = lane & 15, q = lane >> 4;
  f32x4 acc[2][4];
#pragma unroll
  for (int ii = 0; ii < 2; ++ii)
#pragma unroll
    for (int jj = 0; jj < 4; ++jj) acc[ii][jj] = f32x4{0.f, 0.f, 0.f, 0.f};
  const unsigned short* Ab = H + (size_t)b32 * 32 * 1024 + 512;
#pragma unroll
  for (int kt = 0; kt < 8; ++kt) {
    int k0 = kt * 64;
    __syncthreads();
    {
      int p = tid;                                          // 256 slots: 32 rows x 8 chunks
      int row = p >> 3, u = p & 7, ch = u ^ (row & 7);
      async_copy16(Ab + row * 1024 + k0 + ch * 8, ldsA + p * 8);
    }
#pragma unroll
    for (int rd = 0; rd < 8; ++rd) {
      int p = rd * 256 + tid;
      int row = p >> 3, u = p & 7, ch = u ^ (row & 7);
      async_copy16(Wfc1b + row * 512 + k0 + ch * 8, ldsB + p * 8);
    }
    __syncthreads();
#pragma unroll
    for (int s = 0; s < 2; ++s) {
      bf16x8 a[2], b[4];
#pragma unroll
      for (int mf = 0; mf < 2; ++mf) {
        int row = mf * 16 + c16;
        int slot = row * 8 + ((s * 4 + q) ^ (row & 7));
        a[mf] = *(const bf16x8*)(ldsA + slot * 8);
      }
#pragma unroll
      for (int nf = 0; nf < 4; ++nf) {
        int row = wid * 64 + nf * 16 + c16;
        int slot = row * 8 + ((s * 4 + q) ^ (row & 7));
        b[nf] = *(const bf16x8*)(ldsB + slot * 8);
      }
#pragma unroll
      for (int mf = 0; mf < 2; ++mf)
#pragma unroll
        for (int nf = 0; nf < 4; ++nf)
          acc[mf][nf] = __builtin_amdgcn_mfma_f32_16x16x32_bf16(a[mf], b[nf], acc[mf][nf], 0, 0, 0);
    }
  }
  float part[2][2][4];   // [d][mf][r]
#pragma unroll
  for (int d = 0; d < 2; ++d)
#pragma unroll
    for (int mf = 0; mf < 2; ++mf)
#pragma unroll
      for (int r = 0; r < 4; ++r) part[d][mf][r] = 0.f;
#pragma unroll
  for (int nf = 0; nf < 4; ++nf) {
    int col = wid * 64 + nf * 16 + c16;
    float w0 = wfc2s[col], w1 = wfc2s[256 + col], bv = bfc1[col];
#pragma unroll
    for (int mf = 0; mf < 2; ++mf)
#pragma unroll
      for (int r = 0; r < 4; ++r) {
        float v = acc[mf][nf][r] + bv;
        v = v > 0.f ? v : 0.f;
        part[0][mf][r] += v * w0;
        part[1][mf][r] += v * w1;
      }
  }
#pragma unroll
  for (int st = 1; st < 16; st <<= 1)
#pragma unroll
    for (int d = 0; d < 2; ++d)
#pragma unroll
      for (int mf = 0; mf < 2; ++mf)
#pragma unroll
        for (int r = 0; r < 4; ++r)
          part[d][mf][r] += __shfl_xor(part[d][mf][r], st, 64);
  if (c16 == 0) {
#pragma unroll
    for (int mf = 0; mf < 2; ++mf)
#pragma unroll
      for (int r = 0; r < 4; ++r) {
        int rl = mf * 16 + q * 4 + r;                      // 0..31
        red[rl * 8 + wid * 2 + 0] = part[0][mf][r];
        red[rl * 8 + wid * 2 + 1] = part[1][mf][r];
      }
  }
  __syncthreads();
  if (tid < 64) {
    int rl = tid >> 1, d = tid & 1;
    float s = red[rl * 8 + d] + red[rl * 8 + 2 + d] + red[rl * 8 + 4 + d]
            + red[rl * 8 + 6 + d] + bfc2[d];
    int rg = b32 * 32 + rl;
    out[((size_t)rg * T_STEPS + t) * 2 + d] = s;
    posb[rg * 2 + d] = s;
  }
}

// ---------------- launch ----------------
extern "C" void kernel_launch(void* const* d_in, const int* in_sizes, int n_in,
                              void* d_out, int out_size, void* d_ws, size_t ws_size,
                              hipStream_t stream) {
  (void)in_sizes; (void)n_in; (void)out_size;
  const float* ctx   = (const float*)d_in[0];
  const float* pos0  = (const float*)d_in[1];
  const float* ball  = (const float*)d_in[2];
  const int*   roles = (const int*)d_in[3];
  const float* role_table = (const float*)d_in[5];
  const float* Wih0 = (const float*)d_in[6];
  const float* Whh0 = (const float*)d_in[7];
  const float* b0   = (const float*)d_in[8];
  const float* Wih1 = (const float*)d_in[9];
  const float* Whh1 = (const float*)d_in[10];
  const float* b1   = (const float*)d_in[11];
  const float* Wfc1 = (const float*)d_in[12];
  const float* bfc1 = (const float*)d_in[13];
  const float* Wfc2 = (const float*)d_in[14];
  const float* bfc2 = (const float*)d_in[15];
  const float* Winit = (const float*)d_in[16];
  const float* binit = (const float*)d_in[17];
  float* out = (float*)d_out;

  char* w = (char*)d_ws;
  size_t used = 0;
  auto alloc = [&](size_t bytes) {
    char* p = w + used;
    used += (bytes + 255) & ~(size_t)255;
    return p;
  };
  unsigned short* W0p   = (unsigned short*)alloc((size_t)2048 * 512 * 2);
  unsigned short* Wc1p  = (unsigned short*)alloc((size_t)2048 * 1024 * 2);
  unsigned short* Wfc1b = (unsigned short*)alloc((size_t)256 * 512 * 2);
  float* Wposx = (float*)alloc(2048 * 4);
  float* Wposy = (float*)alloc(2048 * 4);
  float* b0p4  = (float*)alloc(2048 * 4);
  float* b1p4  = (float*)alloc(2048 * 4);
  float* posb  = (float*)alloc((size_t)NROWS * 2 * 4);
  unsigned short* Hc0 = (unsigned short*)alloc((size_t)NROWS * 1024 * 2);
  float* c0   = (float*)alloc((size_t)NROWS * 512 * 4);
  float* c1   = (float*)alloc((size_t)NROWS * 512 * 4);
  unsigned short* Hc1 = (unsigned short*)alloc((size_t)NROWS * 1024 * 2);

  const size_t SP_BYTES = (size_t)NROWS * 2048 * 2;           // 92.3 MB
  const bool use_sp = (ws_size >= used + SP_BYTES + (1u << 20));

  unsigned short *Xs, *Wsp, *SP2;
  if (use_sp) {
    SP2 = (unsigned short*)alloc(SP_BYTES);
    Xs  = Hc1;                                 // transient: dead before Hc1 is written
    Wsp = Hc1 + (size_t)NROWS * 384;
  } else {
    SP2 = Hc1;                                 // never dereferenced on lite path
    Xs  = (unsigned short*)alloc((size_t)NROWS * 384 * 2);
    Wsp = (unsigned short*)alloc((size_t)2048 * 384 * 2);
  }

  k_prep_w<<<2048, 512, 0, stream>>>(Whh0, Wih1, Whh1, Wih0, Wfc1, b0, b1,
                                     W0p, Wc1p, Wsp, Wfc1b, Wposx, Wposy, b0p4, b1p4);
  k_init_xs<<<NROWS, 384, 0, stream>>>(ball, ctx, roles, role_table, Xs);
  k_init_state<<<(NROWS * 512 + 255) / 256, 256, 0, stream>>>(pos0, Winit, binit, Hc0, c0, c1, posb);

  if (use_sp) {
    dim3 gs(16, NBM);
    k_static<<<gs, 256, 0, stream>>>(Xs, Wsp, b0p4, SP2);
  }

  for (int t = 0; t < T_STEPS; ++t) {
    unsigned short* cur = (t & 1) ? Hc1 : Hc0;
    unsigned short* nxt = (t & 1) ? Hc0 : Hc1;
    if (use_sp)
      k_s1_8<true><<<704, 512, 0, stream>>>(cur, Xs, W0p, Wsp, SP2, b0p4,
                                            Wposx, Wposy, posb, c0, nxt);
    else
      k_s1_8<false><<<704, 512, 0, stream>>>(cur, Xs, W0p, Wsp, SP2, b0p4,
                                             Wposx, Wposy, posb, c0, nxt);
    k_s2_8<<<704, 512, 0, stream>>>(nxt, cur, Wc1p, b1p4, c1, nxt);
    k_s3<<<704, 256, 0, stream>>>(nxt, Wfc1b, bfc1, Wfc2, bfc2, out, posb, t);
  }
}